// Round 5
// baseline (348.031 us; speedup 1.0000x reference)
//
#include <hip/hip_runtime.h>
#include <cstddef>
#include <cstdint>

#define T_TOK 2048
#define HD 1024
#define ID 1024
#define NE 16
#define TOPK 4
#define BM 128
#define BN 128
#define BK 32
#define MT_MAX 96
#define SLOT_CAP (MT_MAX * BM)

typedef float f32x4 __attribute__((ext_vector_type(4)));
typedef __bf16 bf16x8 __attribute__((ext_vector_type(8)));
typedef __bf16 bf16x4 __attribute__((ext_vector_type(4)));

// ---- workspace layout (bytes) ----
#define WS_TILE_E 256                     // int[MT_MAX]
#define WS_LOGITS (256 + 8192 * 4 * 2 + 1024)  // float[2048*16] (stable offsets)
#define WS_SLOT_TOK (WS_LOGITS + T_TOK * NE * 4)  // int[SLOT_CAP]
#define WS_SLOT_W (WS_SLOT_TOK + SLOT_CAP * 4)    // float[SLOT_CAP]
#define WS_H1 (WS_SLOT_W + SLOT_CAP * 4)          // __bf16[SLOT_CAP][ID]
#define WS_XB (WS_H1 + (size_t)SLOT_CAP * ID * 2)        // __bf16[T][H]
#define WS_W1B (WS_XB + (size_t)T_TOK * HD * 2)          // bf16 E*I*H
#define WS_W2B (WS_W1B + (size_t)NE * ID * HD * 2)
#define WS_W3B (WS_W2B + (size_t)NE * HD * ID * 2)
#define WS_SW1B (WS_W3B + (size_t)NE * ID * HD * 2)
#define WS_SW2B (WS_SW1B + (size_t)ID * HD * 2)
#define WS_SW3B (WS_SW2B + (size_t)HD * ID * 2)
#define WS_NEED (WS_SW3B + (size_t)ID * HD * 2)

__device__ __forceinline__ f32x4 mfma16(bf16x8 a, bf16x8 b, f32x4 c) {
  return __builtin_amdgcn_mfma_f32_16x16x32_bf16(a, b, c, 0, 0, 0);
}

__device__ __forceinline__ void st_bf16x4(__bf16* dst, float4 v) {
  __bf16 tmp[4] = {(__bf16)v.x, (__bf16)v.y, (__bf16)v.z, (__bf16)v.w};
  *(uint2*)dst = *(const uint2*)tmp;
}

// async global(16B/lane) -> LDS, linear dest (m97 pattern)
__device__ __forceinline__ void gload16(const __bf16* g, __bf16* l) {
  __builtin_amdgcn_global_load_lds(
      (const __attribute__((address_space(1))) uint32_t*)g,
      (__attribute__((address_space(3))) uint32_t*)l, 16, 0, 0);
}

// ------------- grid-stride fp32 -> bf16 convert (all tensors) --------------
// All segment sizes are powers of two (float4 units): W4=2^22, S4=2^18, X4=2^19.
#define W4 ((size_t)1 << 22)
#define S4 ((size_t)1 << 18)
#define X4 ((size_t)1 << 19)
#define CVT4_TOTAL (3 * W4 + 3 * S4 + X4)
#define CVT_GRID 2048

__global__ __launch_bounds__(256) void cvt_all(
    const float* __restrict__ w1, const float* __restrict__ w2,
    const float* __restrict__ w3, const float* __restrict__ sw1,
    const float* __restrict__ sw2, const float* __restrict__ sw3,
    const float* __restrict__ x, __bf16* __restrict__ w1b,
    __bf16* __restrict__ w2b, __bf16* __restrict__ w3b,
    __bf16* __restrict__ sw1b, __bf16* __restrict__ sw2b,
    __bf16* __restrict__ sw3b, __bf16* __restrict__ xb) {
  const size_t stride = (size_t)CVT_GRID * 256;
  for (size_t i = (size_t)blockIdx.x * 256 + threadIdx.x; i < CVT4_TOTAL;
       i += stride) {
    const float* src;
    __bf16* dst;
    size_t off;
    if (i < 3 * W4) {
      size_t t = i >> 22;
      off = i & (W4 - 1);
      src = (t == 0) ? w1 : (t == 1) ? w2 : w3;
      dst = (t == 0) ? w1b : (t == 1) ? w2b : w3b;
    } else {
      size_t j = i - 3 * W4;
      if (j < 3 * S4) {
        size_t t = j >> 18;
        off = j & (S4 - 1);
        src = (t == 0) ? sw1 : (t == 1) ? sw2 : sw3;
        dst = (t == 0) ? sw1b : (t == 1) ? sw2b : sw3b;
      } else {
        off = j - 3 * S4;
        src = x;
        dst = xb;
      }
    }
    f32x4 v = __builtin_nontemporal_load((const f32x4*)src + off);
    bf16x4 o = {(__bf16)v[0], (__bf16)v[1], (__bf16)v[2], (__bf16)v[3]};
    *(bf16x4*)(dst + 4 * off) = o;
  }
}

// ---------------- router stage 1: logits = x @ gate_w^T ----------------
__global__ __launch_bounds__(256) void router_logits(
    const float* __restrict__ x, const float* __restrict__ gw,
    float* __restrict__ logits) {
  int tid = threadIdx.x;
  int wv = tid >> 6;
  int lane = tid & 63;
  int tok = blockIdx.x * 4 + wv;
  int e = lane >> 2;
  int q = lane & 3;
  const float4* xr = (const float4*)(x + (size_t)tok * HD) + q * 64;
  const float4* wr = (const float4*)(gw + (size_t)e * HD) + q * 64;
  float s0 = 0.f, s1 = 0.f;
#pragma unroll 8
  for (int i = 0; i < 64; i += 2) {
    float4 a0 = xr[i], w0 = wr[i];
    float4 a1 = xr[i + 1], w1 = wr[i + 1];
    s0 += a0.x * w0.x + a0.y * w0.y + a0.z * w0.z + a0.w * w0.w;
    s1 += a1.x * w1.x + a1.y * w1.y + a1.z * w1.z + a1.w * w1.w;
  }
  float s = s0 + s1;
  s += __shfl_xor(s, 1);
  s += __shfl_xor(s, 2);
  if (q == 0) logits[(size_t)tok * NE + e] = s;
}

// ------- router_finish: top-4 + softmax + scan + scatter (one block) -------
__global__ __launch_bounds__(256) void router_finish(
    const float* __restrict__ logits, const float* __restrict__ bias,
    int* __restrict__ tile_e, int* __restrict__ slot_tok,
    float* __restrict__ slot_w) {
  __shared__ int hist[NE];
  __shared__ int soff[NE + 1];
  __shared__ int fillp[NE];
  __shared__ unsigned lsel[T_TOK];
  __shared__ float4 lw4[T_TOK];

  int tid = threadIdx.x;
  if (tid < NE) { hist[tid] = 0; fillp[tid] = 0; }
  __syncthreads();

  float bb[NE];
#pragma unroll
  for (int e = 0; e < NE; ++e) bb[e] = bias[e];

  // phase A: per-token top-4 + softmax, histogram
  for (int j = 0; j < T_TOK / 256; ++j) {
    int t = tid + 256 * j;
    float lg[NE];
    const float4* lp = (const float4*)(logits + (size_t)t * NE);
#pragma unroll
    for (int q = 0; q < 4; ++q) {
      float4 v = lp[q];
      lg[4 * q] = v.x; lg[4 * q + 1] = v.y; lg[4 * q + 2] = v.z; lg[4 * q + 3] = v.w;
    }
    float b[NE];
#pragma unroll
    for (int e = 0; e < NE; ++e) b[e] = lg[e] + bb[e];

    int selk[TOPK];
    float raw[TOPK];
    unsigned used = 0;
#pragma unroll
    for (int k = 0; k < TOPK; ++k) {
      float best = -3.4e38f;
      int bi = 0;
#pragma unroll
      for (int e = 0; e < NE; ++e) {
        if (!((used >> e) & 1) && b[e] > best) { best = b[e]; bi = e; }
      }
      used |= (1u << bi);
      selk[k] = bi;
      raw[k] = lg[bi];
    }
    float m = raw[0];
#pragma unroll
    for (int k = 1; k < TOPK; ++k) m = fmaxf(m, raw[k]);
    float s = 0.f;
    float w[TOPK];
#pragma unroll
    for (int k = 0; k < TOPK; ++k) { w[k] = __expf(raw[k] - m); s += w[k]; }
    float inv = 1.f / s;
    lsel[t] = (unsigned)selk[0] | ((unsigned)selk[1] << 8) |
              ((unsigned)selk[2] << 16) | ((unsigned)selk[3] << 24);
    lw4[t] = make_float4(w[0] * inv, w[1] * inv, w[2] * inv, w[3] * inv);
#pragma unroll
    for (int k = 0; k < TOPK; ++k) atomicAdd(&hist[selk[k]], 1);
  }
  __syncthreads();

  // phase B: scan + tile_e
  if (tid == 0) {
    int o = 0;
    for (int e = 0; e < NE; ++e) { soff[e] = o; o += (hist[e] + BM - 1) & ~(BM - 1); }
    soff[NE] = o;
  }
  __syncthreads();
  int shared_base = soff[NE];
  int total = shared_base + T_TOK;
  for (int tt = tid; tt < MT_MAX; tt += 256) {
    int base = tt * BM;
    int ee = -1;
    if (base < shared_base) {
      ee = 0;
#pragma unroll
      for (int q = 1; q < NE; ++q) if (base >= soff[q]) ee = q;
    } else if (base < total) {
      ee = NE;
    }
    tile_e[tt] = ee;
  }

  // phase C: scatter routed slots
  for (int j = 0; j < T_TOK / 256; ++j) {
    int t = tid + 256 * j;
    unsigned ps = lsel[t];
    float4 wv = lw4[t];
    int e0 = ps & 255, e1 = (ps >> 8) & 255, e2 = (ps >> 16) & 255, e3 = ps >> 24;
    int p0 = atomicAdd(&fillp[e0], 1);
    slot_tok[soff[e0] + p0] = t; slot_w[soff[e0] + p0] = wv.x;
    int p1 = atomicAdd(&fillp[e1], 1);
    slot_tok[soff[e1] + p1] = t; slot_w[soff[e1] + p1] = wv.y;
    int p2 = atomicAdd(&fillp[e2], 1);
    slot_tok[soff[e2] + p2] = t; slot_w[soff[e2] + p2] = wv.z;
    int p3 = atomicAdd(&fillp[e3], 1);
    slot_tok[soff[e3] + p3] = t; slot_w[soff[e3] + p3] = wv.w;
  }

  // phase D: padding + shared slots (disjoint from phase C writes)
  for (int s = tid; s < shared_base; s += 256) {
    int e = 0;
#pragma unroll
    for (int q = 1; q < NE; ++q) if (s >= soff[q]) e = q;
    if (s >= soff[e] + hist[e]) { slot_tok[s] = -1; slot_w[s] = 0.f; }
  }
  for (int s = shared_base + tid; s < total; s += 256) {
    slot_tok[s] = s - shared_base;
    slot_w[s] = 1.0f;
  }
}

// ============= bf16 GEMMs: dbuf + prefetch + XOR swizzle ====================
// LDS layout per row: 4 chunks of 16B; chunk slot p holds global chunk
// p ^ ((row>>1)&3).  Staged via pre-swizzled GLOBAL source (rule #21),
// read back with kk8 = (kch ^ ((l16>>1)&3))*8.

// pass 1: h1 = silu(x w1^T) * (x w3^T)
__global__ __launch_bounds__(256, 3) void pass1_bf16(
    const __bf16* __restrict__ xb, const int* __restrict__ slot_tok,
    const int* __restrict__ tile_e, const __bf16* __restrict__ w1b,
    const __bf16* __restrict__ w3b, const __bf16* __restrict__ sw1b,
    const __bf16* __restrict__ sw3b, __bf16* __restrict__ h1) {
  int mt = blockIdx.y;
  int e = tile_e[mt];
  if (e < 0) return;
  int n0 = blockIdx.x * BN;
  int m0 = mt * BM;

  const __bf16* wg = (e == NE) ? sw1b : w1b + (size_t)e * ID * HD;
  const __bf16* wu = (e == NE) ? sw3b : w3b + (size_t)e * ID * HD;

  __shared__ __align__(16) __bf16 As[2][BM * BK];
  __shared__ __align__(16) __bf16 Bg[2][BN * BK];
  __shared__ __align__(16) __bf16 Bu[2][BN * BK];

  int tid = threadIdx.x;
  int r0 = tid >> 2, r1 = r0 + 64;
  int c8 = ((tid & 3) ^ ((r0 >> 1) & 3)) * 8;  // pre-swizzled global chunk
  int tok0 = slot_tok[m0 + r0]; if (tok0 < 0) tok0 = 0;
  int tok1 = slot_tok[m0 + r1]; if (tok1 < 0) tok1 = 0;
  const __bf16* gA0 = xb + (size_t)tok0 * HD + c8;
  const __bf16* gA1 = xb + (size_t)tok1 * HD + c8;
  const __bf16* gG0 = wg + (size_t)(n0 + r0) * HD + c8;
  const __bf16* gG1 = wg + (size_t)(n0 + r1) * HD + c8;
  const __bf16* gU0 = wu + (size_t)(n0 + r0) * HD + c8;
  const __bf16* gU1 = wu + (size_t)(n0 + r1) * HD + c8;

  int wave = tid >> 6, lane = tid & 63;
  int wm = (wave >> 1) * 64, wn = (wave & 1) * 64;
  int l16 = lane & 15, kch = lane >> 4;
  int kk8 = (kch ^ ((l16 >> 1) & 3)) * 8;  // swizzled read chunk

  f32x4 accg[4][4] = {};
  f32x4 accu[4][4] = {};

  auto stage = [&](int B, int k0) {
    gload16(gA0 + k0, &As[B][(size_t)tid * 8]);
    gload16(gA1 + k0, &As[B][(size_t)(tid + 256) * 8]);
    gload16(gG0 + k0, &Bg[B][(size_t)tid * 8]);
    gload16(gG1 + k0, &Bg[B][(size_t)(tid + 256) * 8]);
    gload16(gU0 + k0, &Bu[B][(size_t)tid * 8]);
    gload16(gU1 + k0, &Bu[B][(size_t)(tid + 256) * 8]);
  };
  auto compute = [&](int B) {
    bf16x8 af[4], gf[4], uf[4];
#pragma unroll
    for (int i = 0; i < 4; ++i) {
      af[i] = *(const bf16x8*)(&As[B][(wm + i * 16 + l16) * BK + kk8]);
      gf[i] = *(const bf16x8*)(&Bg[B][(wn + i * 16 + l16) * BK + kk8]);
      uf[i] = *(const bf16x8*)(&Bu[B][(wn + i * 16 + l16) * BK + kk8]);
    }
#pragma unroll
    for (int mi = 0; mi < 4; ++mi)
#pragma unroll
      for (int ni = 0; ni < 4; ++ni) {
        accg[mi][ni] = mfma16(af[mi], gf[ni], accg[mi][ni]);
        accu[mi][ni] = mfma16(af[mi], uf[ni], accu[mi][ni]);
      }
  };

  stage(0, 0);
  __syncthreads();
#pragma unroll 1
  for (int k0 = 0; k0 < HD - 2 * BK; k0 += 2 * BK) {
    stage(1, k0 + BK);
    compute(0);
    __syncthreads();
    stage(0, k0 + 2 * BK);
    compute(1);
    __syncthreads();
  }
  stage(1, HD - BK);
  compute(0);
  __syncthreads();
  compute(1);

#pragma unroll
  for (int mi = 0; mi < 4; ++mi) {
#pragma unroll
    for (int ni = 0; ni < 4; ++ni) {
#pragma unroll
      for (int j = 0; j < 4; ++j) {
        int row = m0 + wm + mi * 16 + kch * 4 + j;
        int col = n0 + wn + ni * 16 + l16;
        float g = accg[mi][ni][j];
        float u = accu[mi][ni][j];
        float hv = (g / (1.f + __expf(-g))) * u;
        h1[(size_t)row * ID + col] = (__bf16)hv;
      }
    }
  }
}

// pass 2: out += g * (h1 w2^T)
__global__ __launch_bounds__(256, 3) void pass2_bf16(
    const __bf16* __restrict__ h1, const int* __restrict__ slot_tok,
    const float* __restrict__ slot_w, const int* __restrict__ tile_e,
    const __bf16* __restrict__ w2b, const __bf16* __restrict__ sw2b,
    float* __restrict__ out) {
  int mt = blockIdx.y;
  int e = tile_e[mt];
  if (e < 0) return;
  int n0 = blockIdx.x * BN;
  int m0 = mt * BM;

  const __bf16* wd = (e == NE) ? sw2b : w2b + (size_t)e * HD * ID;

  __shared__ __align__(16) __bf16 As[2][BM * BK];
  __shared__ __align__(16) __bf16 Bs[2][BN * BK];

  int tid = threadIdx.x;
  int r0 = tid >> 2, r1 = r0 + 64;
  int c8 = ((tid & 3) ^ ((r0 >> 1) & 3)) * 8;
  const __bf16* gA0 = h1 + (size_t)(m0 + r0) * ID + c8;
  const __bf16* gA1 = h1 + (size_t)(m0 + r1) * ID + c8;
  const __bf16* gB0 = wd + (size_t)(n0 + r0) * ID + c8;
  const __bf16* gB1 = wd + (size_t)(n0 + r1) * ID + c8;

  int wave = tid >> 6, lane = tid & 63;
  int wm = (wave >> 1) * 64, wn = (wave & 1) * 64;
  int l16 = lane & 15, kch = lane >> 4;
  int kk8 = (kch ^ ((l16 >> 1) & 3)) * 8;

  f32x4 acc[4][4] = {};

  auto stage = [&](int B, int k0) {
    gload16(gA0 + k0, &As[B][(size_t)tid * 8]);
    gload16(gA1 + k0, &As[B][(size_t)(tid + 256) * 8]);
    gload16(gB0 + k0, &Bs[B][(size_t)tid * 8]);
    gload16(gB1 + k0, &Bs[B][(size_t)(tid + 256) * 8]);
  };
  auto compute = [&](int B) {
    bf16x8 af[4], bf[4];
#pragma unroll
    for (int i = 0; i < 4; ++i) {
      af[i] = *(const bf16x8*)(&As[B][(wm + i * 16 + l16) * BK + kk8]);
      bf[i] = *(const bf16x8*)(&Bs[B][(wn + i * 16 + l16) * BK + kk8]);
    }
#pragma unroll
    for (int mi = 0; mi < 4; ++mi)
#pragma unroll
      for (int ni = 0; ni < 4; ++ni)
        acc[mi][ni] = mfma16(af[mi], bf[ni], acc[mi][ni]);
  };

  stage(0, 0);
  __syncthreads();
#pragma unroll 1
  for (int k0 = 0; k0 < ID - 2 * BK; k0 += 2 * BK) {
    stage(1, k0 + BK);
    compute(0);
    __syncthreads();
    stage(0, k0 + 2 * BK);
    compute(1);
    __syncthreads();
  }
  stage(1, ID - BK);
  compute(0);
  __syncthreads();
  compute(1);

#pragma unroll
  for (int mi = 0; mi < 4; ++mi) {
#pragma unroll
    for (int j = 0; j < 4; ++j) {
      int row = m0 + wm + mi * 16 + kch * 4 + j;
      int token = slot_tok[row];
      if (token < 0) continue;
      float wgt = slot_w[row];
#pragma unroll
      for (int ni = 0; ni < 4; ++ni) {
        int col = n0 + wn + ni * 16 + l16;
        atomicAdd(out + (size_t)token * HD + col, wgt * acc[mi][ni][j]);
      }
    }
  }
}

// ============= fp32 fallback path (used only if ws too small) ===============

__global__ __launch_bounds__(256, 2) void pass1_gemm(
    const float* __restrict__ x, const int* __restrict__ slot_tok,
    const int* __restrict__ tile_e, const float* __restrict__ w1,
    const float* __restrict__ w3, const float* __restrict__ sw1,
    const float* __restrict__ sw3, __bf16* __restrict__ h1) {
  int mt = blockIdx.x;
  int e = tile_e[mt];
  if (e < 0) return;
  int n0 = blockIdx.y * BN;
  int m0 = mt * BM;

  const float* wg;
  const float* wu;
  if (e == NE) { wg = sw1; wu = sw3; }
  else { wg = w1 + (size_t)e * ID * HD; wu = w3 + (size_t)e * ID * HD; }

  __shared__ __bf16 As[BM][BK + 8];
  __shared__ __bf16 Bg[BN][BK + 8];
  __shared__ __bf16 Bu[BN][BK + 8];

  int tid = threadIdx.x;
  int lrow = tid >> 1;
  int lcol = (tid & 1) * 16;
  int tokenA = slot_tok[m0 + lrow];
  const float* aptr = x + (size_t)(tokenA < 0 ? 0 : tokenA) * HD + lcol;
  const float* gptr = wg + (size_t)(n0 + lrow) * HD + lcol;
  const float* uptr = wu + (size_t)(n0 + lrow) * HD + lcol;

  int wave = tid >> 6, lane = tid & 63;
  int wm = (wave >> 1) * 64, wn = (wave & 1) * 64;
  int l16 = lane & 15, kch = lane >> 4;

  f32x4 accg[4][4] = {};
  f32x4 accu[4][4] = {};

  for (int k0 = 0; k0 < HD; k0 += BK) {
    float4 av[4], gv[4], uv[4];
#pragma unroll
    for (int j = 0; j < 4; ++j) {
      av[j] = (tokenA >= 0) ? *(const float4*)(aptr + k0 + 4 * j)
                            : make_float4(0.f, 0.f, 0.f, 0.f);
      gv[j] = *(const float4*)(gptr + k0 + 4 * j);
      uv[j] = *(const float4*)(uptr + k0 + 4 * j);
    }
    __syncthreads();
#pragma unroll
    for (int j = 0; j < 4; ++j) {
      st_bf16x4(&As[lrow][lcol + 4 * j], av[j]);
      st_bf16x4(&Bg[lrow][lcol + 4 * j], gv[j]);
      st_bf16x4(&Bu[lrow][lcol + 4 * j], uv[j]);
    }
    __syncthreads();

    bf16x8 af[4], gf[4], uf[4];
#pragma unroll
    for (int i = 0; i < 4; ++i) {
      af[i] = *(const bf16x8*)(&As[wm + i * 16 + l16][kch * 8]);
      gf[i] = *(const bf16x8*)(&Bg[wn + i * 16 + l16][kch * 8]);
      uf[i] = *(const bf16x8*)(&Bu[wn + i * 16 + l16][kch * 8]);
    }
#pragma unroll
    for (int mi = 0; mi < 4; ++mi)
#pragma unroll
      for (int ni = 0; ni < 4; ++ni) {
        accg[mi][ni] = mfma16(af[mi], gf[ni], accg[mi][ni]);
        accu[mi][ni] = mfma16(af[mi], uf[ni], accu[mi][ni]);
      }
  }

#pragma unroll
  for (int mi = 0; mi < 4; ++mi) {
#pragma unroll
    for (int ni = 0; ni < 4; ++ni) {
#pragma unroll
      for (int j = 0; j < 4; ++j) {
        int row = m0 + wm + mi * 16 + kch * 4 + j;
        int col = n0 + wn + ni * 16 + l16;
        float g = accg[mi][ni][j];
        float u = accu[mi][ni][j];
        float hv = (g / (1.f + __expf(-g))) * u;
        h1[(size_t)row * ID + col] = (__bf16)hv;
      }
    }
  }
}

__global__ __launch_bounds__(256, 2) void pass2_gemm(
    const __bf16* __restrict__ h1, const int* __restrict__ slot_tok,
    const float* __restrict__ slot_w, const int* __restrict__ tile_e,
    const float* __restrict__ w2, const float* __restrict__ sw2,
    float* __restrict__ out) {
  int mt = blockIdx.x;
  int e = tile_e[mt];
  if (e < 0) return;
  int n0 = blockIdx.y * BN;
  int m0 = mt * BM;

  const float* wd = (e == NE) ? sw2 : (w2 + (size_t)e * HD * ID);

  __shared__ __bf16 As[BM][BK + 8];
  __shared__ __bf16 Bs[BN][BK + 8];

  int tid = threadIdx.x;
  int lrow = tid >> 1;
  int lcol = (tid & 1) * 16;
  const __bf16* aptr = h1 + (size_t)(m0 + lrow) * ID + lcol;
  const float* bptr = wd + (size_t)(n0 + lrow) * ID + lcol;

  int wave = tid >> 6, lane = tid & 63;
  int wm = (wave >> 1) * 64, wn = (wave & 1) * 64;
  int l16 = lane & 15, kch = lane >> 4;

  f32x4 acc[4][4] = {};

  for (int k0 = 0; k0 < ID; k0 += BK) {
    uint4 a0 = *(const uint4*)(aptr + k0);
    uint4 a1 = *(const uint4*)(aptr + k0 + 8);
    float4 bv[4];
#pragma unroll
    for (int j = 0; j < 4; ++j) bv[j] = *(const float4*)(bptr + k0 + 4 * j);
    __syncthreads();
    *(uint4*)(&As[lrow][lcol]) = a0;
    *(uint4*)(&As[lrow][lcol + 8]) = a1;
#pragma unroll
    for (int j = 0; j < 4; ++j) st_bf16x4(&Bs[lrow][lcol + 4 * j], bv[j]);
    __syncthreads();

    bf16x8 af[4], bf[4];
#pragma unroll
    for (int i = 0; i < 4; ++i) {
      af[i] = *(const bf16x8*)(&As[wm + i * 16 + l16][kch * 8]);
      bf[i] = *(const bf16x8*)(&Bs[wn + i * 16 + l16][kch * 8]);
    }
#pragma unroll
    for (int mi = 0; mi < 4; ++mi)
#pragma unroll
      for (int ni = 0; ni < 4; ++ni)
        acc[mi][ni] = mfma16(af[mi], bf[ni], acc[mi][ni]);
  }

#pragma unroll
  for (int mi = 0; mi < 4; ++mi) {
#pragma unroll
    for (int j = 0; j < 4; ++j) {
      int row = m0 + wm + mi * 16 + kch * 4 + j;
      int token = slot_tok[row];
      if (token < 0) continue;
      float wgt = slot_w[row];
#pragma unroll
      for (int ni = 0; ni < 4; ++ni) {
        int col = n0 + wn + ni * 16 + l16;
        atomicAdd(out + (size_t)token * HD + col, wgt * acc[mi][ni][j]);
      }
    }
  }
}

// ---------------- launcher ----------------
extern "C" void kernel_launch(void* const* d_in, const int* in_sizes, int n_in,
                              void* d_out, int out_size, void* d_ws, size_t ws_size,
                              hipStream_t stream) {
  const float* x = (const float*)d_in[0];
  const float* gate_w = (const float*)d_in[1];
  const float* ebias = (const float*)d_in[2];
  const float* w1 = (const float*)d_in[3];
  const float* w2 = (const float*)d_in[4];
  const float* w3 = (const float*)d_in[5];
  const float* sw1 = (const float*)d_in[6];
  const float* sw2 = (const float*)d_in[7];
  const float* sw3 = (const float*)d_in[8];
  float* out = (float*)d_out;

  char* ws = (char*)d_ws;
  int* tile_e = (int*)(ws + WS_TILE_E);
  float* logits = (float*)(ws + WS_LOGITS);
  int* slot_tok = (int*)(ws + WS_SLOT_TOK);
  float* slot_w = (float*)(ws + WS_SLOT_W);
  __bf16* h1 = (__bf16*)(ws + WS_H1);

  hipMemsetAsync(d_out, 0, (size_t)T_TOK * HD * sizeof(float), stream);

  if (ws_size >= WS_NEED) {
    __bf16* xb = (__bf16*)(ws + WS_XB);
    __bf16* w1b = (__bf16*)(ws + WS_W1B);
    __bf16* w2b = (__bf16*)(ws + WS_W2B);
    __bf16* w3b = (__bf16*)(ws + WS_W3B);
    __bf16* sw1b = (__bf16*)(ws + WS_SW1B);
    __bf16* sw2b = (__bf16*)(ws + WS_SW2B);
    __bf16* sw3b = (__bf16*)(ws + WS_SW3B);

    router_logits<<<T_TOK / 4, 256, 0, stream>>>(x, gate_w, logits);
    cvt_all<<<CVT_GRID, 256, 0, stream>>>(w1, w2, w3, sw1, sw2, sw3, x, w1b, w2b,
                                          w3b, sw1b, sw2b, sw3b, xb);
    router_finish<<<1, 256, 0, stream>>>(logits, ebias, tile_e, slot_tok, slot_w);

    pass1_bf16<<<dim3(ID / BN, MT_MAX), 256, 0, stream>>>(
        xb, slot_tok, tile_e, w1b, w3b, sw1b, sw3b, h1);
    pass2_bf16<<<dim3(HD / BN, MT_MAX), 256, 0, stream>>>(
        h1, slot_tok, slot_w, tile_e, w2b, sw2b, out);
  } else {
    router_logits<<<T_TOK / 4, 256, 0, stream>>>(x, gate_w, logits);
    router_finish<<<1, 256, 0, stream>>>(logits, ebias, tile_e, slot_tok, slot_w);
    pass1_gemm<<<dim3(MT_MAX, ID / BN), 256, 0, stream>>>(x, slot_tok, tile_e, w1,
                                                          w3, sw1, sw3, h1);
    pass2_gemm<<<dim3(MT_MAX, HD / BN), 256, 0, stream>>>(h1, slot_tok, slot_w,
                                                          tile_e, w2, sw2, out);
  }
}

// Round 6
// 260.463 us; speedup vs baseline: 1.3362x; 1.3362x over previous
//
#include <hip/hip_runtime.h>
#include <cstddef>
#include <cstdint>

#define T_TOK 2048
#define HD 1024
#define ID 1024
#define NE 16
#define TOPK 4
#define BM 128
#define BN 128
#define BK 32
#define MT_MAX 96
#define SLOT_CAP (MT_MAX * BM)

typedef float f32x4 __attribute__((ext_vector_type(4)));
typedef __bf16 bf16x8 __attribute__((ext_vector_type(8)));
typedef __bf16 bf16x4 __attribute__((ext_vector_type(4)));

// ---- workspace layout (bytes) ----
#define WS_TILE_E 256                     // int[MT_MAX]
#define WS_LOGITS (256 + 8192 * 4 * 2 + 1024)  // float[2048*16]
#define WS_SLOT_TOK (WS_LOGITS + T_TOK * NE * 4)  // int[SLOT_CAP]
#define WS_SLOT_W (WS_SLOT_TOK + SLOT_CAP * 4)    // float[SLOT_CAP]
#define WS_H1 (WS_SLOT_W + SLOT_CAP * 4)          // __bf16[SLOT_CAP][ID]
#define WS_XB (WS_H1 + (size_t)SLOT_CAP * ID * 2)        // __bf16[T][H]
#define WS_W1B (WS_XB + (size_t)T_TOK * HD * 2)          // bf16 E*I*H
#define WS_W2B (WS_W1B + (size_t)NE * ID * HD * 2)
#define WS_W3B (WS_W2B + (size_t)NE * HD * ID * 2)
#define WS_SW1B (WS_W3B + (size_t)NE * ID * HD * 2)
#define WS_SW2B (WS_SW1B + (size_t)ID * HD * 2)
#define WS_SW3B (WS_SW2B + (size_t)HD * ID * 2)
#define WS_NEED (WS_SW3B + (size_t)ID * HD * 2)

__device__ __forceinline__ f32x4 mfma16(bf16x8 a, bf16x8 b, f32x4 c) {
  return __builtin_amdgcn_mfma_f32_16x16x32_bf16(a, b, c, 0, 0, 0);
}

__device__ __forceinline__ void st_bf16x4(__bf16* dst, float4 v) {
  __bf16 tmp[4] = {(__bf16)v.x, (__bf16)v.y, (__bf16)v.z, (__bf16)v.w};
  *(uint2*)dst = *(const uint2*)tmp;
}

// async global(16B/lane) -> LDS, linear dest (m97 pattern)
__device__ __forceinline__ void gload16(const __bf16* g, __bf16* l) {
  __builtin_amdgcn_global_load_lds(
      (const __attribute__((address_space(1))) uint32_t*)g,
      (__attribute__((address_space(3))) uint32_t*)l, 16, 0, 0);
}

// ------------- grid-stride fp32 -> bf16 convert (all tensors) --------------
#define W4 ((size_t)1 << 22)
#define S4 ((size_t)1 << 18)
#define X4 ((size_t)1 << 19)
#define CVT4_TOTAL (3 * W4 + 3 * S4 + X4)
#define CVT_GRID 2048

__global__ __launch_bounds__(256) void cvt_all(
    const float* __restrict__ w1, const float* __restrict__ w2,
    const float* __restrict__ w3, const float* __restrict__ sw1,
    const float* __restrict__ sw2, const float* __restrict__ sw3,
    const float* __restrict__ x, __bf16* __restrict__ w1b,
    __bf16* __restrict__ w2b, __bf16* __restrict__ w3b,
    __bf16* __restrict__ sw1b, __bf16* __restrict__ sw2b,
    __bf16* __restrict__ sw3b, __bf16* __restrict__ xb) {
  const size_t stride = (size_t)CVT_GRID * 256;
  for (size_t i = (size_t)blockIdx.x * 256 + threadIdx.x; i < CVT4_TOTAL;
       i += stride) {
    const float* src;
    __bf16* dst;
    size_t off;
    if (i < 3 * W4) {
      size_t t = i >> 22;
      off = i & (W4 - 1);
      src = (t == 0) ? w1 : (t == 1) ? w2 : w3;
      dst = (t == 0) ? w1b : (t == 1) ? w2b : w3b;
    } else {
      size_t j = i - 3 * W4;
      if (j < 3 * S4) {
        size_t t = j >> 18;
        off = j & (S4 - 1);
        src = (t == 0) ? sw1 : (t == 1) ? sw2 : sw3;
        dst = (t == 0) ? sw1b : (t == 1) ? sw2b : sw3b;
      } else {
        off = j - 3 * S4;
        src = x;
        dst = xb;
      }
    }
    f32x4 v = __builtin_nontemporal_load((const f32x4*)src + off);
    bf16x4 o = {(__bf16)v[0], (__bf16)v[1], (__bf16)v[2], (__bf16)v[3]};
    *(bf16x4*)(dst + 4 * off) = o;
  }
}

// ---------------- router stage 1: logits = x @ gate_w^T ----------------
__global__ __launch_bounds__(256) void router_logits(
    const float* __restrict__ x, const float* __restrict__ gw,
    float* __restrict__ logits) {
  int tid = threadIdx.x;
  int wv = tid >> 6;
  int lane = tid & 63;
  int tok = blockIdx.x * 4 + wv;
  int e = lane >> 2;
  int q = lane & 3;
  const float4* xr = (const float4*)(x + (size_t)tok * HD) + q * 64;
  const float4* wr = (const float4*)(gw + (size_t)e * HD) + q * 64;
  float s0 = 0.f, s1 = 0.f;
#pragma unroll 8
  for (int i = 0; i < 64; i += 2) {
    float4 a0 = xr[i], w0 = wr[i];
    float4 a1 = xr[i + 1], w1 = wr[i + 1];
    s0 += a0.x * w0.x + a0.y * w0.y + a0.z * w0.z + a0.w * w0.w;
    s1 += a1.x * w1.x + a1.y * w1.y + a1.z * w1.z + a1.w * w1.w;
  }
  float s = s0 + s1;
  s += __shfl_xor(s, 1);
  s += __shfl_xor(s, 2);
  if (q == 0) logits[(size_t)tok * NE + e] = s;
}

// ------- router_finish: top-4 + softmax + scan + scatter (one block) -------
__global__ __launch_bounds__(256) void router_finish(
    const float* __restrict__ logits, const float* __restrict__ bias,
    int* __restrict__ tile_e, int* __restrict__ slot_tok,
    float* __restrict__ slot_w) {
  __shared__ int hist[NE];
  __shared__ int soff[NE + 1];
  __shared__ int fillp[NE];
  __shared__ unsigned lsel[T_TOK];
  __shared__ float4 lw4[T_TOK];

  int tid = threadIdx.x;
  if (tid < NE) { hist[tid] = 0; fillp[tid] = 0; }
  __syncthreads();

  float bb[NE];
#pragma unroll
  for (int e = 0; e < NE; ++e) bb[e] = bias[e];

  // phase A: per-token top-4 + softmax, histogram
  for (int j = 0; j < T_TOK / 256; ++j) {
    int t = tid + 256 * j;
    float lg[NE];
    const float4* lp = (const float4*)(logits + (size_t)t * NE);
#pragma unroll
    for (int q = 0; q < 4; ++q) {
      float4 v = lp[q];
      lg[4 * q] = v.x; lg[4 * q + 1] = v.y; lg[4 * q + 2] = v.z; lg[4 * q + 3] = v.w;
    }
    float b[NE];
#pragma unroll
    for (int e = 0; e < NE; ++e) b[e] = lg[e] + bb[e];

    int selk[TOPK];
    float raw[TOPK];
    unsigned used = 0;
#pragma unroll
    for (int k = 0; k < TOPK; ++k) {
      float best = -3.4e38f;
      int bi = 0;
#pragma unroll
      for (int e = 0; e < NE; ++e) {
        if (!((used >> e) & 1) && b[e] > best) { best = b[e]; bi = e; }
      }
      used |= (1u << bi);
      selk[k] = bi;
      raw[k] = lg[bi];
    }
    float m = raw[0];
#pragma unroll
    for (int k = 1; k < TOPK; ++k) m = fmaxf(m, raw[k]);
    float s = 0.f;
    float w[TOPK];
#pragma unroll
    for (int k = 0; k < TOPK; ++k) { w[k] = __expf(raw[k] - m); s += w[k]; }
    float inv = 1.f / s;
    lsel[t] = (unsigned)selk[0] | ((unsigned)selk[1] << 8) |
              ((unsigned)selk[2] << 16) | ((unsigned)selk[3] << 24);
    lw4[t] = make_float4(w[0] * inv, w[1] * inv, w[2] * inv, w[3] * inv);
#pragma unroll
    for (int k = 0; k < TOPK; ++k) atomicAdd(&hist[selk[k]], 1);
  }
  __syncthreads();

  // phase B: scan + tile_e
  if (tid == 0) {
    int o = 0;
    for (int e = 0; e < NE; ++e) { soff[e] = o; o += (hist[e] + BM - 1) & ~(BM - 1); }
    soff[NE] = o;
  }
  __syncthreads();
  int shared_base = soff[NE];
  int total = shared_base + T_TOK;
  for (int tt = tid; tt < MT_MAX; tt += 256) {
    int base = tt * BM;
    int ee = -1;
    if (base < shared_base) {
      ee = 0;
#pragma unroll
      for (int q = 1; q < NE; ++q) if (base >= soff[q]) ee = q;
    } else if (base < total) {
      ee = NE;
    }
    tile_e[tt] = ee;
  }

  // phase C: scatter routed slots
  for (int j = 0; j < T_TOK / 256; ++j) {
    int t = tid + 256 * j;
    unsigned ps = lsel[t];
    float4 wv = lw4[t];
    int e0 = ps & 255, e1 = (ps >> 8) & 255, e2 = (ps >> 16) & 255, e3 = ps >> 24;
    int p0 = atomicAdd(&fillp[e0], 1);
    slot_tok[soff[e0] + p0] = t; slot_w[soff[e0] + p0] = wv.x;
    int p1 = atomicAdd(&fillp[e1], 1);
    slot_tok[soff[e1] + p1] = t; slot_w[soff[e1] + p1] = wv.y;
    int p2 = atomicAdd(&fillp[e2], 1);
    slot_tok[soff[e2] + p2] = t; slot_w[soff[e2] + p2] = wv.z;
    int p3 = atomicAdd(&fillp[e3], 1);
    slot_tok[soff[e3] + p3] = t; slot_w[soff[e3] + p3] = wv.w;
  }

  // phase D: padding + shared slots (disjoint from phase C writes)
  for (int s = tid; s < shared_base; s += 256) {
    int e = 0;
#pragma unroll
    for (int q = 1; q < NE; ++q) if (s >= soff[q]) e = q;
    if (s >= soff[e] + hist[e]) { slot_tok[s] = -1; slot_w[s] = 0.f; }
  }
  for (int s = shared_base + tid; s < total; s += 256) {
    slot_tok[s] = s - shared_base;
    slot_w[s] = 1.0f;
  }
}

// ============= bf16 GEMMs: dbuf + prefetch + XOR swizzle ====================
// LDS row = 4 chunks of 16B; slot p holds global chunk p ^ ((row>>1)&3).
// Staged via pre-swizzled GLOBAL source (rule #21), read back with
// kk8 = (kch ^ ((l16>>1)&3))*8.

// pass 1: h1 = silu(x w1^T) * (x w3^T)
// NOTE: (256,2) NOT (256,3): accg+accu alone = 128 regs; 3 waves/EU caps the
// allocator at ~170 and forces accumulator spill to scratch (round-5: WRITE_SIZE
// 390 MB, 2x dur). 2 waves/EU -> 256-reg budget, no spill.
__global__ __launch_bounds__(256, 2) void pass1_bf16(
    const __bf16* __restrict__ xb, const int* __restrict__ slot_tok,
    const int* __restrict__ tile_e, const __bf16* __restrict__ w1b,
    const __bf16* __restrict__ w3b, const __bf16* __restrict__ sw1b,
    const __bf16* __restrict__ sw3b, __bf16* __restrict__ h1) {
  int mt = blockIdx.y;
  int e = tile_e[mt];
  if (e < 0) return;
  int n0 = blockIdx.x * BN;
  int m0 = mt * BM;

  const __bf16* wg = (e == NE) ? sw1b : w1b + (size_t)e * ID * HD;
  const __bf16* wu = (e == NE) ? sw3b : w3b + (size_t)e * ID * HD;

  __shared__ __align__(16) __bf16 As[2][BM * BK];
  __shared__ __align__(16) __bf16 Bg[2][BN * BK];
  __shared__ __align__(16) __bf16 Bu[2][BN * BK];

  int tid = threadIdx.x;
  int r0 = tid >> 2, r1 = r0 + 64;
  int c8 = ((tid & 3) ^ ((r0 >> 1) & 3)) * 8;  // pre-swizzled global chunk
  int tok0 = slot_tok[m0 + r0]; if (tok0 < 0) tok0 = 0;
  int tok1 = slot_tok[m0 + r1]; if (tok1 < 0) tok1 = 0;
  const __bf16* gA0 = xb + (size_t)tok0 * HD + c8;
  const __bf16* gA1 = xb + (size_t)tok1 * HD + c8;
  const __bf16* gG0 = wg + (size_t)(n0 + r0) * HD + c8;
  const __bf16* gG1 = wg + (size_t)(n0 + r1) * HD + c8;
  const __bf16* gU0 = wu + (size_t)(n0 + r0) * HD + c8;
  const __bf16* gU1 = wu + (size_t)(n0 + r1) * HD + c8;

  int wave = tid >> 6, lane = tid & 63;
  int wm = (wave >> 1) * 64, wn = (wave & 1) * 64;
  int l16 = lane & 15, kch = lane >> 4;
  int kk8 = (kch ^ ((l16 >> 1) & 3)) * 8;  // swizzled read chunk

  f32x4 accg[4][4] = {};
  f32x4 accu[4][4] = {};

  auto stage = [&](int B, int k0) {
    gload16(gA0 + k0, &As[B][(size_t)tid * 8]);
    gload16(gA1 + k0, &As[B][(size_t)(tid + 256) * 8]);
    gload16(gG0 + k0, &Bg[B][(size_t)tid * 8]);
    gload16(gG1 + k0, &Bg[B][(size_t)(tid + 256) * 8]);
    gload16(gU0 + k0, &Bu[B][(size_t)tid * 8]);
    gload16(gU1 + k0, &Bu[B][(size_t)(tid + 256) * 8]);
  };
  auto compute = [&](int B) {
    bf16x8 af[4], gf[4], uf[4];
#pragma unroll
    for (int i = 0; i < 4; ++i) {
      af[i] = *(const bf16x8*)(&As[B][(wm + i * 16 + l16) * BK + kk8]);
      gf[i] = *(const bf16x8*)(&Bg[B][(wn + i * 16 + l16) * BK + kk8]);
      uf[i] = *(const bf16x8*)(&Bu[B][(wn + i * 16 + l16) * BK + kk8]);
    }
#pragma unroll
    for (int mi = 0; mi < 4; ++mi)
#pragma unroll
      for (int ni = 0; ni < 4; ++ni) {
        accg[mi][ni] = mfma16(af[mi], gf[ni], accg[mi][ni]);
        accu[mi][ni] = mfma16(af[mi], uf[ni], accu[mi][ni]);
      }
  };

  stage(0, 0);
  __syncthreads();
#pragma unroll 1
  for (int k0 = 0; k0 < HD - 2 * BK; k0 += 2 * BK) {
    stage(1, k0 + BK);
    compute(0);
    __syncthreads();
    stage(0, k0 + 2 * BK);
    compute(1);
    __syncthreads();
  }
  stage(1, HD - BK);
  compute(0);
  __syncthreads();
  compute(1);

#pragma unroll
  for (int mi = 0; mi < 4; ++mi) {
#pragma unroll
    for (int ni = 0; ni < 4; ++ni) {
#pragma unroll
      for (int j = 0; j < 4; ++j) {
        int row = m0 + wm + mi * 16 + kch * 4 + j;
        int col = n0 + wn + ni * 16 + l16;
        float g = accg[mi][ni][j];
        float u = accu[mi][ni][j];
        float hv = (g / (1.f + __expf(-g))) * u;
        h1[(size_t)row * ID + col] = (__bf16)hv;
      }
    }
  }
}

// pass 2: out += g * (h1 w2^T)   (acc = 64 regs; (256,3) fits without spill)
__global__ __launch_bounds__(256, 3) void pass2_bf16(
    const __bf16* __restrict__ h1, const int* __restrict__ slot_tok,
    const float* __restrict__ slot_w, const int* __restrict__ tile_e,
    const __bf16* __restrict__ w2b, const __bf16* __restrict__ sw2b,
    float* __restrict__ out) {
  int mt = blockIdx.y;
  int e = tile_e[mt];
  if (e < 0) return;
  int n0 = blockIdx.x * BN;
  int m0 = mt * BM;

  const __bf16* wd = (e == NE) ? sw2b : w2b + (size_t)e * HD * ID;

  __shared__ __align__(16) __bf16 As[2][BM * BK];
  __shared__ __align__(16) __bf16 Bs[2][BN * BK];

  int tid = threadIdx.x;
  int r0 = tid >> 2, r1 = r0 + 64;
  int c8 = ((tid & 3) ^ ((r0 >> 1) & 3)) * 8;
  const __bf16* gA0 = h1 + (size_t)(m0 + r0) * ID + c8;
  const __bf16* gA1 = h1 + (size_t)(m0 + r1) * ID + c8;
  const __bf16* gB0 = wd + (size_t)(n0 + r0) * ID + c8;
  const __bf16* gB1 = wd + (size_t)(n0 + r1) * ID + c8;

  int wave = tid >> 6, lane = tid & 63;
  int wm = (wave >> 1) * 64, wn = (wave & 1) * 64;
  int l16 = lane & 15, kch = lane >> 4;
  int kk8 = (kch ^ ((l16 >> 1) & 3)) * 8;

  f32x4 acc[4][4] = {};

  auto stage = [&](int B, int k0) {
    gload16(gA0 + k0, &As[B][(size_t)tid * 8]);
    gload16(gA1 + k0, &As[B][(size_t)(tid + 256) * 8]);
    gload16(gB0 + k0, &Bs[B][(size_t)tid * 8]);
    gload16(gB1 + k0, &Bs[B][(size_t)(tid + 256) * 8]);
  };
  auto compute = [&](int B) {
    bf16x8 af[4], bf[4];
#pragma unroll
    for (int i = 0; i < 4; ++i) {
      af[i] = *(const bf16x8*)(&As[B][(wm + i * 16 + l16) * BK + kk8]);
      bf[i] = *(const bf16x8*)(&Bs[B][(wn + i * 16 + l16) * BK + kk8]);
    }
#pragma unroll
    for (int mi = 0; mi < 4; ++mi)
#pragma unroll
      for (int ni = 0; ni < 4; ++ni)
        acc[mi][ni] = mfma16(af[mi], bf[ni], acc[mi][ni]);
  };

  stage(0, 0);
  __syncthreads();
#pragma unroll 1
  for (int k0 = 0; k0 < ID - 2 * BK; k0 += 2 * BK) {
    stage(1, k0 + BK);
    compute(0);
    __syncthreads();
    stage(0, k0 + 2 * BK);
    compute(1);
    __syncthreads();
  }
  stage(1, ID - BK);
  compute(0);
  __syncthreads();
  compute(1);

#pragma unroll
  for (int mi = 0; mi < 4; ++mi) {
#pragma unroll
    for (int j = 0; j < 4; ++j) {
      int row = m0 + wm + mi * 16 + kch * 4 + j;
      int token = slot_tok[row];
      if (token < 0) continue;
      float wgt = slot_w[row];
#pragma unroll
      for (int ni = 0; ni < 4; ++ni) {
        int col = n0 + wn + ni * 16 + l16;
        atomicAdd(out + (size_t)token * HD + col, wgt * acc[mi][ni][j]);
      }
    }
  }
}

// ============= fp32 fallback path (used only if ws too small) ===============

__global__ __launch_bounds__(256, 2) void pass1_gemm(
    const float* __restrict__ x, const int* __restrict__ slot_tok,
    const int* __restrict__ tile_e, const float* __restrict__ w1,
    const float* __restrict__ w3, const float* __restrict__ sw1,
    const float* __restrict__ sw3, __bf16* __restrict__ h1) {
  int mt = blockIdx.x;
  int e = tile_e[mt];
  if (e < 0) return;
  int n0 = blockIdx.y * BN;
  int m0 = mt * BM;

  const float* wg;
  const float* wu;
  if (e == NE) { wg = sw1; wu = sw3; }
  else { wg = w1 + (size_t)e * ID * HD; wu = w3 + (size_t)e * ID * HD; }

  __shared__ __bf16 As[BM][BK + 8];
  __shared__ __bf16 Bg[BN][BK + 8];
  __shared__ __bf16 Bu[BN][BK + 8];

  int tid = threadIdx.x;
  int lrow = tid >> 1;
  int lcol = (tid & 1) * 16;
  int tokenA = slot_tok[m0 + lrow];
  const float* aptr = x + (size_t)(tokenA < 0 ? 0 : tokenA) * HD + lcol;
  const float* gptr = wg + (size_t)(n0 + lrow) * HD + lcol;
  const float* uptr = wu + (size_t)(n0 + lrow) * HD + lcol;

  int wave = tid >> 6, lane = tid & 63;
  int wm = (wave >> 1) * 64, wn = (wave & 1) * 64;
  int l16 = lane & 15, kch = lane >> 4;

  f32x4 accg[4][4] = {};
  f32x4 accu[4][4] = {};

  for (int k0 = 0; k0 < HD; k0 += BK) {
    float4 av[4], gv[4], uv[4];
#pragma unroll
    for (int j = 0; j < 4; ++j) {
      av[j] = (tokenA >= 0) ? *(const float4*)(aptr + k0 + 4 * j)
                            : make_float4(0.f, 0.f, 0.f, 0.f);
      gv[j] = *(const float4*)(gptr + k0 + 4 * j);
      uv[j] = *(const float4*)(uptr + k0 + 4 * j);
    }
    __syncthreads();
#pragma unroll
    for (int j = 0; j < 4; ++j) {
      st_bf16x4(&As[lrow][lcol + 4 * j], av[j]);
      st_bf16x4(&Bg[lrow][lcol + 4 * j], gv[j]);
      st_bf16x4(&Bu[lrow][lcol + 4 * j], uv[j]);
    }
    __syncthreads();

    bf16x8 af[4], gf[4], uf[4];
#pragma unroll
    for (int i = 0; i < 4; ++i) {
      af[i] = *(const bf16x8*)(&As[wm + i * 16 + l16][kch * 8]);
      gf[i] = *(const bf16x8*)(&Bg[wn + i * 16 + l16][kch * 8]);
      uf[i] = *(const bf16x8*)(&Bu[wn + i * 16 + l16][kch * 8]);
    }
#pragma unroll
    for (int mi = 0; mi < 4; ++mi)
#pragma unroll
      for (int ni = 0; ni < 4; ++ni) {
        accg[mi][ni] = mfma16(af[mi], gf[ni], accg[mi][ni]);
        accu[mi][ni] = mfma16(af[mi], uf[ni], accu[mi][ni]);
      }
  }

#pragma unroll
  for (int mi = 0; mi < 4; ++mi) {
#pragma unroll
    for (int ni = 0; ni < 4; ++ni) {
#pragma unroll
      for (int j = 0; j < 4; ++j) {
        int row = m0 + wm + mi * 16 + kch * 4 + j;
        int col = n0 + wn + ni * 16 + l16;
        float g = accg[mi][ni][j];
        float u = accu[mi][ni][j];
        float hv = (g / (1.f + __expf(-g))) * u;
        h1[(size_t)row * ID + col] = (__bf16)hv;
      }
    }
  }
}

__global__ __launch_bounds__(256, 2) void pass2_gemm(
    const __bf16* __restrict__ h1, const int* __restrict__ slot_tok,
    const float* __restrict__ slot_w, const int* __restrict__ tile_e,
    const float* __restrict__ w2, const float* __restrict__ sw2,
    float* __restrict__ out) {
  int mt = blockIdx.x;
  int e = tile_e[mt];
  if (e < 0) return;
  int n0 = blockIdx.y * BN;
  int m0 = mt * BM;

  const float* wd = (e == NE) ? sw2 : (w2 + (size_t)e * HD * ID);

  __shared__ __bf16 As[BM][BK + 8];
  __shared__ __bf16 Bs[BN][BK + 8];

  int tid = threadIdx.x;
  int lrow = tid >> 1;
  int lcol = (tid & 1) * 16;
  const __bf16* aptr = h1 + (size_t)(m0 + lrow) * ID + lcol;
  const float* bptr = wd + (size_t)(n0 + lrow) * ID + lcol;

  int wave = tid >> 6, lane = tid & 63;
  int wm = (wave >> 1) * 64, wn = (wave & 1) * 64;
  int l16 = lane & 15, kch = lane >> 4;

  f32x4 acc[4][4] = {};

  for (int k0 = 0; k0 < ID; k0 += BK) {
    uint4 a0 = *(const uint4*)(aptr + k0);
    uint4 a1 = *(const uint4*)(aptr + k0 + 8);
    float4 bv[4];
#pragma unroll
    for (int j = 0; j < 4; ++j) bv[j] = *(const float4*)(bptr + k0 + 4 * j);
    __syncthreads();
    *(uint4*)(&As[lrow][lcol]) = a0;
    *(uint4*)(&As[lrow][lcol + 8]) = a1;
#pragma unroll
    for (int j = 0; j < 4; ++j) st_bf16x4(&Bs[lrow][lcol + 4 * j], bv[j]);
    __syncthreads();

    bf16x8 af[4], bf[4];
#pragma unroll
    for (int i = 0; i < 4; ++i) {
      af[i] = *(const bf16x8*)(&As[wm + i * 16 + l16][kch * 8]);
      bf[i] = *(const bf16x8*)(&Bs[wn + i * 16 + l16][kch * 8]);
    }
#pragma unroll
    for (int mi = 0; mi < 4; ++mi)
#pragma unroll
      for (int ni = 0; ni < 4; ++ni)
        acc[mi][ni] = mfma16(af[mi], bf[ni], acc[mi][ni]);
  }

#pragma unroll
  for (int mi = 0; mi < 4; ++mi) {
#pragma unroll
    for (int j = 0; j < 4; ++j) {
      int row = m0 + wm + mi * 16 + kch * 4 + j;
      int token = slot_tok[row];
      if (token < 0) continue;
      float wgt = slot_w[row];
#pragma unroll
      for (int ni = 0; ni < 4; ++ni) {
        int col = n0 + wn + ni * 16 + l16;
        atomicAdd(out + (size_t)token * HD + col, wgt * acc[mi][ni][j]);
      }
    }
  }
}

// ---------------- launcher ----------------
extern "C" void kernel_launch(void* const* d_in, const int* in_sizes, int n_in,
                              void* d_out, int out_size, void* d_ws, size_t ws_size,
                              hipStream_t stream) {
  const float* x = (const float*)d_in[0];
  const float* gate_w = (const float*)d_in[1];
  const float* ebias = (const float*)d_in[2];
  const float* w1 = (const float*)d_in[3];
  const float* w2 = (const float*)d_in[4];
  const float* w3 = (const float*)d_in[5];
  const float* sw1 = (const float*)d_in[6];
  const float* sw2 = (const float*)d_in[7];
  const float* sw3 = (const float*)d_in[8];
  float* out = (float*)d_out;

  char* ws = (char*)d_ws;
  int* tile_e = (int*)(ws + WS_TILE_E);
  float* logits = (float*)(ws + WS_LOGITS);
  int* slot_tok = (int*)(ws + WS_SLOT_TOK);
  float* slot_w = (float*)(ws + WS_SLOT_W);
  __bf16* h1 = (__bf16*)(ws + WS_H1);

  hipMemsetAsync(d_out, 0, (size_t)T_TOK * HD * sizeof(float), stream);

  if (ws_size >= WS_NEED) {
    __bf16* xb = (__bf16*)(ws + WS_XB);
    __bf16* w1b = (__bf16*)(ws + WS_W1B);
    __bf16* w2b = (__bf16*)(ws + WS_W2B);
    __bf16* w3b = (__bf16*)(ws + WS_W3B);
    __bf16* sw1b = (__bf16*)(ws + WS_SW1B);
    __bf16* sw2b = (__bf16*)(ws + WS_SW2B);
    __bf16* sw3b = (__bf16*)(ws + WS_SW3B);

    router_logits<<<T_TOK / 4, 256, 0, stream>>>(x, gate_w, logits);
    cvt_all<<<CVT_GRID, 256, 0, stream>>>(w1, w2, w3, sw1, sw2, sw3, x, w1b, w2b,
                                          w3b, sw1b, sw2b, sw3b, xb);
    router_finish<<<1, 256, 0, stream>>>(logits, ebias, tile_e, slot_tok, slot_w);

    pass1_bf16<<<dim3(ID / BN, MT_MAX), 256, 0, stream>>>(
        xb, slot_tok, tile_e, w1b, w3b, sw1b, sw3b, h1);
    pass2_bf16<<<dim3(HD / BN, MT_MAX), 256, 0, stream>>>(
        h1, slot_tok, slot_w, tile_e, w2b, sw2b, out);
  } else {
    router_logits<<<T_TOK / 4, 256, 0, stream>>>(x, gate_w, logits);
    router_finish<<<1, 256, 0, stream>>>(logits, ebias, tile_e, slot_tok, slot_w);
    pass1_gemm<<<dim3(MT_MAX, ID / BN), 256, 0, stream>>>(x, slot_tok, tile_e, w1,
                                                          w3, sw1, sw3, h1);
    pass2_gemm<<<dim3(MT_MAX, HD / BN), 256, 0, stream>>>(h1, slot_tok, slot_w,
                                                          tile_e, w2, sw2, out);
  }
}

// Round 7
// 256.614 us; speedup vs baseline: 1.3562x; 1.0150x over previous
//
#include <hip/hip_runtime.h>
#include <cstddef>
#include <cstdint>

#define T_TOK 2048
#define HD 1024
#define ID 1024
#define NE 16
#define TOPK 4
#define BM 128
#define BN 128
#define BK 32
#define MT_MAX 96
#define SLOT_CAP (MT_MAX * BM)

typedef float f32x4 __attribute__((ext_vector_type(4)));
typedef __bf16 bf16x8 __attribute__((ext_vector_type(8)));
typedef __bf16 bf16x4 __attribute__((ext_vector_type(4)));

// ---- workspace layout (bytes) ----
#define WS_TILE_E 256                     // int[MT_MAX]
#define WS_LOGITS (256 + 8192 * 4 * 2 + 1024)  // float[2048*16]
#define WS_SLOT_TOK (WS_LOGITS + T_TOK * NE * 4)  // int[SLOT_CAP]
#define WS_SLOT_W (WS_SLOT_TOK + SLOT_CAP * 4)    // float[SLOT_CAP]
#define WS_H1 (WS_SLOT_W + SLOT_CAP * 4)          // __bf16[SLOT_CAP][ID]
#define WS_XB (WS_H1 + (size_t)SLOT_CAP * ID * 2)        // __bf16[T][H]
#define WS_W1B (WS_XB + (size_t)T_TOK * HD * 2)          // bf16 E*I*H
#define WS_W2B (WS_W1B + (size_t)NE * ID * HD * 2)
#define WS_W3B (WS_W2B + (size_t)NE * HD * ID * 2)
#define WS_SW1B (WS_W3B + (size_t)NE * ID * HD * 2)
#define WS_SW2B (WS_SW1B + (size_t)ID * HD * 2)
#define WS_SW3B (WS_SW2B + (size_t)HD * ID * 2)
#define WS_NEED (WS_SW3B + (size_t)ID * HD * 2)

__device__ __forceinline__ f32x4 mfma16(bf16x8 a, bf16x8 b, f32x4 c) {
  return __builtin_amdgcn_mfma_f32_16x16x32_bf16(a, b, c, 0, 0, 0);
}

__device__ __forceinline__ void st_bf16x4(__bf16* dst, float4 v) {
  __bf16 tmp[4] = {(__bf16)v.x, (__bf16)v.y, (__bf16)v.z, (__bf16)v.w};
  *(uint2*)dst = *(const uint2*)tmp;
}

// async global(16B/lane) -> LDS, linear dest (m97 pattern)
__device__ __forceinline__ void gload16(const __bf16* g, __bf16* l) {
  __builtin_amdgcn_global_load_lds(
      (const __attribute__((address_space(1))) uint32_t*)g,
      (__attribute__((address_space(3))) uint32_t*)l, 16, 0, 0);
}

// ---------------- fused: router logits (512 blocks) + cvt (2048) ----------
#define W4 ((size_t)1 << 22)
#define S4 ((size_t)1 << 18)
#define X4 ((size_t)1 << 19)
#define CVT4_TOTAL (3 * W4 + 3 * S4 + X4)
#define CVT_GRID 2048
#define LOGITS_BLOCKS (T_TOK / 4)

__global__ __launch_bounds__(256) void fused_pre(
    const float* __restrict__ w1, const float* __restrict__ w2,
    const float* __restrict__ w3, const float* __restrict__ sw1,
    const float* __restrict__ sw2, const float* __restrict__ sw3,
    const float* __restrict__ x, __bf16* __restrict__ w1b,
    __bf16* __restrict__ w2b, __bf16* __restrict__ w3b,
    __bf16* __restrict__ sw1b, __bf16* __restrict__ sw2b,
    __bf16* __restrict__ sw3b, __bf16* __restrict__ xb,
    const float* __restrict__ gw, float* __restrict__ logits) {
  int tid = threadIdx.x;
  if ((int)blockIdx.x < LOGITS_BLOCKS) {
    // ---- router logits: 4 waves/block, 1 token/wave, lane=(e,q) ----
    int wv = tid >> 6;
    int lane = tid & 63;
    int tok = blockIdx.x * 4 + wv;
    int e = lane >> 2;
    int q = lane & 3;
    const float4* xr = (const float4*)(x + (size_t)tok * HD) + q * 64;
    const float4* wr = (const float4*)(gw + (size_t)e * HD) + q * 64;
    float s0 = 0.f, s1 = 0.f;
#pragma unroll 8
    for (int i = 0; i < 64; i += 2) {
      float4 a0 = xr[i], w0 = wr[i];
      float4 a1 = xr[i + 1], w1v = wr[i + 1];
      s0 += a0.x * w0.x + a0.y * w0.y + a0.z * w0.z + a0.w * w0.w;
      s1 += a1.x * w1v.x + a1.y * w1v.y + a1.z * w1v.z + a1.w * w1v.w;
    }
    float s = s0 + s1;
    s += __shfl_xor(s, 1);
    s += __shfl_xor(s, 2);
    if (q == 0) logits[(size_t)tok * NE + e] = s;
    return;
  }
  // ---- grid-stride cvt over pow-2 segments ----
  size_t b = blockIdx.x - LOGITS_BLOCKS;
  const size_t stride = (size_t)CVT_GRID * 256;
  for (size_t i = b * 256 + tid; i < CVT4_TOTAL; i += stride) {
    const float* src;
    __bf16* dst;
    size_t off;
    if (i < 3 * W4) {
      size_t t = i >> 22;
      off = i & (W4 - 1);
      src = (t == 0) ? w1 : (t == 1) ? w2 : w3;
      dst = (t == 0) ? w1b : (t == 1) ? w2b : w3b;
    } else {
      size_t j = i - 3 * W4;
      if (j < 3 * S4) {
        size_t t = j >> 18;
        off = j & (S4 - 1);
        src = (t == 0) ? sw1 : (t == 1) ? sw2 : sw3;
        dst = (t == 0) ? sw1b : (t == 1) ? sw2b : sw3b;
      } else {
        off = j - 3 * S4;
        src = x;
        dst = xb;
      }
    }
    f32x4 v = __builtin_nontemporal_load((const f32x4*)src + off);
    bf16x4 o = {(__bf16)v[0], (__bf16)v[1], (__bf16)v[2], (__bf16)v[3]};
    *(bf16x4*)(dst + 4 * off) = o;
  }
}

// fallback standalone logits (fp32 path)
__global__ __launch_bounds__(256) void router_logits(
    const float* __restrict__ x, const float* __restrict__ gw,
    float* __restrict__ logits) {
  int tid = threadIdx.x;
  int wv = tid >> 6;
  int lane = tid & 63;
  int tok = blockIdx.x * 4 + wv;
  int e = lane >> 2;
  int q = lane & 3;
  const float4* xr = (const float4*)(x + (size_t)tok * HD) + q * 64;
  const float4* wr = (const float4*)(gw + (size_t)e * HD) + q * 64;
  float s0 = 0.f, s1 = 0.f;
#pragma unroll 8
  for (int i = 0; i < 64; i += 2) {
    float4 a0 = xr[i], w0 = wr[i];
    float4 a1 = xr[i + 1], w1 = wr[i + 1];
    s0 += a0.x * w0.x + a0.y * w0.y + a0.z * w0.z + a0.w * w0.w;
    s1 += a1.x * w1.x + a1.y * w1.y + a1.z * w1.z + a1.w * w1.w;
  }
  float s = s0 + s1;
  s += __shfl_xor(s, 1);
  s += __shfl_xor(s, 2);
  if (q == 0) logits[(size_t)tok * NE + e] = s;
}

// ------- router_finish: top-4 + softmax + scan + scatter (one block) -------
__global__ __launch_bounds__(256) void router_finish(
    const float* __restrict__ logits, const float* __restrict__ bias,
    int* __restrict__ tile_e, int* __restrict__ slot_tok,
    float* __restrict__ slot_w) {
  __shared__ int hist[NE];
  __shared__ int soff[NE + 1];
  __shared__ int fillp[NE];
  __shared__ unsigned lsel[T_TOK];
  __shared__ float4 lw4[T_TOK];

  int tid = threadIdx.x;
  if (tid < NE) { hist[tid] = 0; fillp[tid] = 0; }
  __syncthreads();

  float bb[NE];
#pragma unroll
  for (int e = 0; e < NE; ++e) bb[e] = bias[e];

  for (int j = 0; j < T_TOK / 256; ++j) {
    int t = tid + 256 * j;
    float lg[NE];
    const float4* lp = (const float4*)(logits + (size_t)t * NE);
#pragma unroll
    for (int q = 0; q < 4; ++q) {
      float4 v = lp[q];
      lg[4 * q] = v.x; lg[4 * q + 1] = v.y; lg[4 * q + 2] = v.z; lg[4 * q + 3] = v.w;
    }
    float b[NE];
#pragma unroll
    for (int e = 0; e < NE; ++e) b[e] = lg[e] + bb[e];

    int selk[TOPK];
    float raw[TOPK];
    unsigned used = 0;
#pragma unroll
    for (int k = 0; k < TOPK; ++k) {
      float best = -3.4e38f;
      int bi = 0;
#pragma unroll
      for (int e = 0; e < NE; ++e) {
        if (!((used >> e) & 1) && b[e] > best) { best = b[e]; bi = e; }
      }
      used |= (1u << bi);
      selk[k] = bi;
      raw[k] = lg[bi];
    }
    float m = raw[0];
#pragma unroll
    for (int k = 1; k < TOPK; ++k) m = fmaxf(m, raw[k]);
    float s = 0.f;
    float w[TOPK];
#pragma unroll
    for (int k = 0; k < TOPK; ++k) { w[k] = __expf(raw[k] - m); s += w[k]; }
    float inv = 1.f / s;
    lsel[t] = (unsigned)selk[0] | ((unsigned)selk[1] << 8) |
              ((unsigned)selk[2] << 16) | ((unsigned)selk[3] << 24);
    lw4[t] = make_float4(w[0] * inv, w[1] * inv, w[2] * inv, w[3] * inv);
#pragma unroll
    for (int k = 0; k < TOPK; ++k) atomicAdd(&hist[selk[k]], 1);
  }
  __syncthreads();

  if (tid == 0) {
    int o = 0;
    for (int e = 0; e < NE; ++e) { soff[e] = o; o += (hist[e] + BM - 1) & ~(BM - 1); }
    soff[NE] = o;
  }
  __syncthreads();
  int shared_base = soff[NE];
  int total = shared_base + T_TOK;
  for (int tt = tid; tt < MT_MAX; tt += 256) {
    int base = tt * BM;
    int ee = -1;
    if (base < shared_base) {
      ee = 0;
#pragma unroll
      for (int q = 1; q < NE; ++q) if (base >= soff[q]) ee = q;
    } else if (base < total) {
      ee = NE;
    }
    tile_e[tt] = ee;
  }

  for (int j = 0; j < T_TOK / 256; ++j) {
    int t = tid + 256 * j;
    unsigned ps = lsel[t];
    float4 wv = lw4[t];
    int e0 = ps & 255, e1 = (ps >> 8) & 255, e2 = (ps >> 16) & 255, e3 = ps >> 24;
    int p0 = atomicAdd(&fillp[e0], 1);
    slot_tok[soff[e0] + p0] = t; slot_w[soff[e0] + p0] = wv.x;
    int p1 = atomicAdd(&fillp[e1], 1);
    slot_tok[soff[e1] + p1] = t; slot_w[soff[e1] + p1] = wv.y;
    int p2 = atomicAdd(&fillp[e2], 1);
    slot_tok[soff[e2] + p2] = t; slot_w[soff[e2] + p2] = wv.z;
    int p3 = atomicAdd(&fillp[e3], 1);
    slot_tok[soff[e3] + p3] = t; slot_w[soff[e3] + p3] = wv.w;
  }

  for (int s = tid; s < shared_base; s += 256) {
    int e = 0;
#pragma unroll
    for (int q = 1; q < NE; ++q) if (s >= soff[q]) e = q;
    if (s >= soff[e] + hist[e]) { slot_tok[s] = -1; slot_w[s] = 0.f; }
  }
  for (int s = shared_base + tid; s < total; s += 256) {
    slot_tok[s] = s - shared_base;
    slot_w[s] = 1.0f;
  }
}

// ===== bf16 GEMMs: dbuf + COUNTED vmcnt pipeline (T3/T4) + XOR swizzle ======
// Per iter: stage(next) -> vmcnt(N) [waits only prev stage; next stays in
// flight] -> s_barrier -> ds_read -> lgkmcnt(0) -> s_barrier [buffer free]
// -> MFMA.  NO vmcnt(0) in loop: prefetch spans the full iteration.
// Raw s_barrier (not __syncthreads) avoids the compiler's vmcnt(0) drain.

// pass 1: h1 = silu(x w1^T) * (x w3^T).  (256,2): accs=128 regs, 3/EU spills.
__global__ __launch_bounds__(256, 2) void pass1_bf16(
    const __bf16* __restrict__ xb, const int* __restrict__ slot_tok,
    const int* __restrict__ tile_e, const __bf16* __restrict__ w1b,
    const __bf16* __restrict__ w3b, const __bf16* __restrict__ sw1b,
    const __bf16* __restrict__ sw3b, __bf16* __restrict__ h1) {
  int mt = blockIdx.y;
  int e = tile_e[mt];
  if (e < 0) return;
  int n0 = blockIdx.x * BN;
  int m0 = mt * BM;

  const __bf16* wg = (e == NE) ? sw1b : w1b + (size_t)e * ID * HD;
  const __bf16* wu = (e == NE) ? sw3b : w3b + (size_t)e * ID * HD;

  __shared__ __align__(16) __bf16 As[2][BM * BK];
  __shared__ __align__(16) __bf16 Bg[2][BN * BK];
  __shared__ __align__(16) __bf16 Bu[2][BN * BK];

  int tid = threadIdx.x;
  int r0 = tid >> 2, r1 = r0 + 64;
  int c8 = ((tid & 3) ^ ((r0 >> 1) & 3)) * 8;  // pre-swizzled global chunk
  int tok0 = slot_tok[m0 + r0]; if (tok0 < 0) tok0 = 0;
  int tok1 = slot_tok[m0 + r1]; if (tok1 < 0) tok1 = 0;
  const __bf16* gA0 = xb + (size_t)tok0 * HD + c8;
  const __bf16* gA1 = xb + (size_t)tok1 * HD + c8;
  const __bf16* gG0 = wg + (size_t)(n0 + r0) * HD + c8;
  const __bf16* gG1 = wg + (size_t)(n0 + r1) * HD + c8;
  const __bf16* gU0 = wu + (size_t)(n0 + r0) * HD + c8;
  const __bf16* gU1 = wu + (size_t)(n0 + r1) * HD + c8;

  int wave = tid >> 6, lane = tid & 63;
  int wm = (wave >> 1) * 64, wn = (wave & 1) * 64;
  int l16 = lane & 15, kch = lane >> 4;
  int kk8 = (kch ^ ((l16 >> 1) & 3)) * 8;  // swizzled read chunk

  f32x4 accg[4][4] = {};
  f32x4 accu[4][4] = {};

  auto stage = [&](int B, int k0) {
    gload16(gA0 + k0, &As[B][(size_t)tid * 8]);
    gload16(gA1 + k0, &As[B][(size_t)(tid + 256) * 8]);
    gload16(gG0 + k0, &Bg[B][(size_t)tid * 8]);
    gload16(gG1 + k0, &Bg[B][(size_t)(tid + 256) * 8]);
    gload16(gU0 + k0, &Bu[B][(size_t)tid * 8]);
    gload16(gU1 + k0, &Bu[B][(size_t)(tid + 256) * 8]);
  };
  auto body = [&](int B) {
    bf16x8 af[4], gf[4], uf[4];
#pragma unroll
    for (int i = 0; i < 4; ++i) {
      af[i] = *(const bf16x8*)(&As[B][(wm + i * 16 + l16) * BK + kk8]);
      gf[i] = *(const bf16x8*)(&Bg[B][(wn + i * 16 + l16) * BK + kk8]);
      uf[i] = *(const bf16x8*)(&Bu[B][(wn + i * 16 + l16) * BK + kk8]);
    }
    asm volatile("s_waitcnt lgkmcnt(0)" ::: "memory");
    __builtin_amdgcn_s_barrier();            // buffer free for next stage
    __builtin_amdgcn_sched_barrier(0);       // rule #18: pin MFMAs below
#pragma unroll
    for (int mi = 0; mi < 4; ++mi)
#pragma unroll
      for (int ni = 0; ni < 4; ++ni) {
        accg[mi][ni] = mfma16(af[mi], gf[ni], accg[mi][ni]);
        accu[mi][ni] = mfma16(af[mi], uf[ni], accu[mi][ni]);
      }
  };

  stage(0, 0);
#pragma unroll 1
  for (int k = 0; k < HD / BK - 1; ++k) {
    int cur = k & 1;
    stage(cur ^ 1, (k + 1) * BK);            // 6 loads stay in flight
    asm volatile("s_waitcnt vmcnt(6)" ::: "memory");  // prev stage landed (mine)
    __builtin_amdgcn_s_barrier();            // ...and everyone's
    __builtin_amdgcn_sched_barrier(0);
    body(cur);
  }
  asm volatile("s_waitcnt vmcnt(0)" ::: "memory");
  __builtin_amdgcn_s_barrier();
  __builtin_amdgcn_sched_barrier(0);
  body((HD / BK - 1) & 1);

#pragma unroll
  for (int mi = 0; mi < 4; ++mi) {
#pragma unroll
    for (int ni = 0; ni < 4; ++ni) {
#pragma unroll
      for (int j = 0; j < 4; ++j) {
        int row = m0 + wm + mi * 16 + kch * 4 + j;
        int col = n0 + wn + ni * 16 + l16;
        float g = accg[mi][ni][j];
        float u = accu[mi][ni][j];
        float hv = (g / (1.f + __expf(-g))) * u;
        h1[(size_t)row * ID + col] = (__bf16)hv;
      }
    }
  }
}

// pass 2: out += g * (h1 w2^T)
__global__ __launch_bounds__(256, 3) void pass2_bf16(
    const __bf16* __restrict__ h1, const int* __restrict__ slot_tok,
    const float* __restrict__ slot_w, const int* __restrict__ tile_e,
    const __bf16* __restrict__ w2b, const __bf16* __restrict__ sw2b,
    float* __restrict__ out) {
  int mt = blockIdx.y;
  int e = tile_e[mt];
  if (e < 0) return;
  int n0 = blockIdx.x * BN;
  int m0 = mt * BM;

  const __bf16* wd = (e == NE) ? sw2b : w2b + (size_t)e * HD * ID;

  __shared__ __align__(16) __bf16 As[2][BM * BK];
  __shared__ __align__(16) __bf16 Bs[2][BN * BK];

  int tid = threadIdx.x;
  int r0 = tid >> 2, r1 = r0 + 64;
  int c8 = ((tid & 3) ^ ((r0 >> 1) & 3)) * 8;
  const __bf16* gA0 = h1 + (size_t)(m0 + r0) * ID + c8;
  const __bf16* gA1 = h1 + (size_t)(m0 + r1) * ID + c8;
  const __bf16* gB0 = wd + (size_t)(n0 + r0) * ID + c8;
  const __bf16* gB1 = wd + (size_t)(n0 + r1) * ID + c8;

  int wave = tid >> 6, lane = tid & 63;
  int wm = (wave >> 1) * 64, wn = (wave & 1) * 64;
  int l16 = lane & 15, kch = lane >> 4;
  int kk8 = (kch ^ ((l16 >> 1) & 3)) * 8;

  f32x4 acc[4][4] = {};

  auto stage = [&](int B, int k0) {
    gload16(gA0 + k0, &As[B][(size_t)tid * 8]);
    gload16(gA1 + k0, &As[B][(size_t)(tid + 256) * 8]);
    gload16(gB0 + k0, &Bs[B][(size_t)tid * 8]);
    gload16(gB1 + k0, &Bs[B][(size_t)(tid + 256) * 8]);
  };
  auto body = [&](int B) {
    bf16x8 af[4], bf[4];
#pragma unroll
    for (int i = 0; i < 4; ++i) {
      af[i] = *(const bf16x8*)(&As[B][(wm + i * 16 + l16) * BK + kk8]);
      bf[i] = *(const bf16x8*)(&Bs[B][(wn + i * 16 + l16) * BK + kk8]);
    }
    asm volatile("s_waitcnt lgkmcnt(0)" ::: "memory");
    __builtin_amdgcn_s_barrier();
    __builtin_amdgcn_sched_barrier(0);
#pragma unroll
    for (int mi = 0; mi < 4; ++mi)
#pragma unroll
      for (int ni = 0; ni < 4; ++ni)
        acc[mi][ni] = mfma16(af[mi], bf[ni], acc[mi][ni]);
  };

  stage(0, 0);
#pragma unroll 1
  for (int k = 0; k < ID / BK - 1; ++k) {
    int cur = k & 1;
    stage(cur ^ 1, (k + 1) * BK);
    asm volatile("s_waitcnt vmcnt(4)" ::: "memory");
    __builtin_amdgcn_s_barrier();
    __builtin_amdgcn_sched_barrier(0);
    body(cur);
  }
  asm volatile("s_waitcnt vmcnt(0)" ::: "memory");
  __builtin_amdgcn_s_barrier();
  __builtin_amdgcn_sched_barrier(0);
  body((ID / BK - 1) & 1);

#pragma unroll
  for (int mi = 0; mi < 4; ++mi) {
#pragma unroll
    for (int j = 0; j < 4; ++j) {
      int row = m0 + wm + mi * 16 + kch * 4 + j;
      int token = slot_tok[row];
      if (token < 0) continue;
      float wgt = slot_w[row];
#pragma unroll
      for (int ni = 0; ni < 4; ++ni) {
        int col = n0 + wn + ni * 16 + l16;
        atomicAdd(out + (size_t)token * HD + col, wgt * acc[mi][ni][j]);
      }
    }
  }
}

// ============= fp32 fallback path (used only if ws too small) ===============

__global__ __launch_bounds__(256, 2) void pass1_gemm(
    const float* __restrict__ x, const int* __restrict__ slot_tok,
    const int* __restrict__ tile_e, const float* __restrict__ w1,
    const float* __restrict__ w3, const float* __restrict__ sw1,
    const float* __restrict__ sw3, __bf16* __restrict__ h1) {
  int mt = blockIdx.x;
  int e = tile_e[mt];
  if (e < 0) return;
  int n0 = blockIdx.y * BN;
  int m0 = mt * BM;

  const float* wg;
  const float* wu;
  if (e == NE) { wg = sw1; wu = sw3; }
  else { wg = w1 + (size_t)e * ID * HD; wu = w3 + (size_t)e * ID * HD; }

  __shared__ __bf16 As[BM][BK + 8];
  __shared__ __bf16 Bg[BN][BK + 8];
  __shared__ __bf16 Bu[BN][BK + 8];

  int tid = threadIdx.x;
  int lrow = tid >> 1;
  int lcol = (tid & 1) * 16;
  int tokenA = slot_tok[m0 + lrow];
  const float* aptr = x + (size_t)(tokenA < 0 ? 0 : tokenA) * HD + lcol;
  const float* gptr = wg + (size_t)(n0 + lrow) * HD + lcol;
  const float* uptr = wu + (size_t)(n0 + lrow) * HD + lcol;

  int wave = tid >> 6, lane = tid & 63;
  int wm = (wave >> 1) * 64, wn = (wave & 1) * 64;
  int l16 = lane & 15, kch = lane >> 4;

  f32x4 accg[4][4] = {};
  f32x4 accu[4][4] = {};

  for (int k0 = 0; k0 < HD; k0 += BK) {
    float4 av[4], gv[4], uv[4];
#pragma unroll
    for (int j = 0; j < 4; ++j) {
      av[j] = (tokenA >= 0) ? *(const float4*)(aptr + k0 + 4 * j)
                            : make_float4(0.f, 0.f, 0.f, 0.f);
      gv[j] = *(const float4*)(gptr + k0 + 4 * j);
      uv[j] = *(const float4*)(uptr + k0 + 4 * j);
    }
    __syncthreads();
#pragma unroll
    for (int j = 0; j < 4; ++j) {
      st_bf16x4(&As[lrow][lcol + 4 * j], av[j]);
      st_bf16x4(&Bg[lrow][lcol + 4 * j], gv[j]);
      st_bf16x4(&Bu[lrow][lcol + 4 * j], uv[j]);
    }
    __syncthreads();

    bf16x8 af[4], gf[4], uf[4];
#pragma unroll
    for (int i = 0; i < 4; ++i) {
      af[i] = *(const bf16x8*)(&As[wm + i * 16 + l16][kch * 8]);
      gf[i] = *(const bf16x8*)(&Bg[wn + i * 16 + l16][kch * 8]);
      uf[i] = *(const bf16x8*)(&Bu[wn + i * 16 + l16][kch * 8]);
    }
#pragma unroll
    for (int mi = 0; mi < 4; ++mi)
#pragma unroll
      for (int ni = 0; ni < 4; ++ni) {
        accg[mi][ni] = mfma16(af[mi], gf[ni], accg[mi][ni]);
        accu[mi][ni] = mfma16(af[mi], uf[ni], accu[mi][ni]);
      }
  }

#pragma unroll
  for (int mi = 0; mi < 4; ++mi) {
#pragma unroll
    for (int ni = 0; ni < 4; ++ni) {
#pragma unroll
      for (int j = 0; j < 4; ++j) {
        int row = m0 + wm + mi * 16 + kch * 4 + j;
        int col = n0 + wn + ni * 16 + l16;
        float g = accg[mi][ni][j];
        float u = accu[mi][ni][j];
        float hv = (g / (1.f + __expf(-g))) * u;
        h1[(size_t)row * ID + col] = (__bf16)hv;
      }
    }
  }
}

__global__ __launch_bounds__(256, 2) void pass2_gemm(
    const __bf16* __restrict__ h1, const int* __restrict__ slot_tok,
    const float* __restrict__ slot_w, const int* __restrict__ tile_e,
    const float* __restrict__ w2, const float* __restrict__ sw2,
    float* __restrict__ out) {
  int mt = blockIdx.x;
  int e = tile_e[mt];
  if (e < 0) return;
  int n0 = blockIdx.y * BN;
  int m0 = mt * BM;

  const float* wd = (e == NE) ? sw2 : (w2 + (size_t)e * HD * ID);

  __shared__ __bf16 As[BM][BK + 8];
  __shared__ __bf16 Bs[BN][BK + 8];

  int tid = threadIdx.x;
  int lrow = tid >> 1;
  int lcol = (tid & 1) * 16;
  const __bf16* aptr = h1 + (size_t)(m0 + lrow) * ID + lcol;
  const float* bptr = wd + (size_t)(n0 + lrow) * ID + lcol;

  int wave = tid >> 6, lane = tid & 63;
  int wm = (wave >> 1) * 64, wn = (wave & 1) * 64;
  int l16 = lane & 15, kch = lane >> 4;

  f32x4 acc[4][4] = {};

  for (int k0 = 0; k0 < ID; k0 += BK) {
    uint4 a0 = *(const uint4*)(aptr + k0);
    uint4 a1 = *(const uint4*)(aptr + k0 + 8);
    float4 bv[4];
#pragma unroll
    for (int j = 0; j < 4; ++j) bv[j] = *(const float4*)(bptr + k0 + 4 * j);
    __syncthreads();
    *(uint4*)(&As[lrow][lcol]) = a0;
    *(uint4*)(&As[lrow][lcol + 8]) = a1;
#pragma unroll
    for (int j = 0; j < 4; ++j) st_bf16x4(&Bs[lrow][lcol + 4 * j], bv[j]);
    __syncthreads();

    bf16x8 af[4], bf[4];
#pragma unroll
    for (int i = 0; i < 4; ++i) {
      af[i] = *(const bf16x8*)(&As[wm + i * 16 + l16][kch * 8]);
      bf[i] = *(const bf16x8*)(&Bs[wn + i * 16 + l16][kch * 8]);
    }
#pragma unroll
    for (int mi = 0; mi < 4; ++mi)
#pragma unroll
      for (int ni = 0; ni < 4; ++ni)
        acc[mi][ni] = mfma16(af[mi], bf[ni], acc[mi][ni]);
  }

#pragma unroll
  for (int mi = 0; mi < 4; ++mi) {
#pragma unroll
    for (int j = 0; j < 4; ++j) {
      int row = m0 + wm + mi * 16 + kch * 4 + j;
      int token = slot_tok[row];
      if (token < 0) continue;
      float wgt = slot_w[row];
#pragma unroll
      for (int ni = 0; ni < 4; ++ni) {
        int col = n0 + wn + ni * 16 + l16;
        atomicAdd(out + (size_t)token * HD + col, wgt * acc[mi][ni][j]);
      }
    }
  }
}

// ---------------- launcher ----------------
extern "C" void kernel_launch(void* const* d_in, const int* in_sizes, int n_in,
                              void* d_out, int out_size, void* d_ws, size_t ws_size,
                              hipStream_t stream) {
  const float* x = (const float*)d_in[0];
  const float* gate_w = (const float*)d_in[1];
  const float* ebias = (const float*)d_in[2];
  const float* w1 = (const float*)d_in[3];
  const float* w2 = (const float*)d_in[4];
  const float* w3 = (const float*)d_in[5];
  const float* sw1 = (const float*)d_in[6];
  const float* sw2 = (const float*)d_in[7];
  const float* sw3 = (const float*)d_in[8];
  float* out = (float*)d_out;

  char* ws = (char*)d_ws;
  int* tile_e = (int*)(ws + WS_TILE_E);
  float* logits = (float*)(ws + WS_LOGITS);
  int* slot_tok = (int*)(ws + WS_SLOT_TOK);
  float* slot_w = (float*)(ws + WS_SLOT_W);
  __bf16* h1 = (__bf16*)(ws + WS_H1);

  hipMemsetAsync(d_out, 0, (size_t)T_TOK * HD * sizeof(float), stream);

  if (ws_size >= WS_NEED) {
    __bf16* xb = (__bf16*)(ws + WS_XB);
    __bf16* w1b = (__bf16*)(ws + WS_W1B);
    __bf16* w2b = (__bf16*)(ws + WS_W2B);
    __bf16* w3b = (__bf16*)(ws + WS_W3B);
    __bf16* sw1b = (__bf16*)(ws + WS_SW1B);
    __bf16* sw2b = (__bf16*)(ws + WS_SW2B);
    __bf16* sw3b = (__bf16*)(ws + WS_SW3B);

    fused_pre<<<LOGITS_BLOCKS + CVT_GRID, 256, 0, stream>>>(
        w1, w2, w3, sw1, sw2, sw3, x, w1b, w2b, w3b, sw1b, sw2b, sw3b, xb,
        gate_w, logits);
    router_finish<<<1, 256, 0, stream>>>(logits, ebias, tile_e, slot_tok, slot_w);

    pass1_bf16<<<dim3(ID / BN, MT_MAX), 256, 0, stream>>>(
        xb, slot_tok, tile_e, w1b, w3b, sw1b, sw3b, h1);
    pass2_bf16<<<dim3(HD / BN, MT_MAX), 256, 0, stream>>>(
        h1, slot_tok, slot_w, tile_e, w2b, sw2b, out);
  } else {
    router_logits<<<T_TOK / 4, 256, 0, stream>>>(x, gate_w, logits);
    router_finish<<<1, 256, 0, stream>>>(logits, ebias, tile_e, slot_tok, slot_w);
    pass1_gemm<<<dim3(MT_MAX, ID / BN), 256, 0, stream>>>(x, slot_tok, tile_e, w1,
                                                          w3, sw1, sw3, h1);
    pass2_gemm<<<dim3(MT_MAX, HD / BN), 256, 0, stream>>>(h1, slot_tok, slot_w,
                                                          tile_e, w2, sw2, out);
  }
}